// Round 6
// baseline (57.212 us; speedup 1.0000x reference)
//
#include <hip/hip_runtime.h>
#include <math.h>

#define B_ 1000
#define D_ 8
#define PRE_ 98
#define NXT_ 2048
#define J_ 32
#define K_ 64
#define A_ 5

typedef __attribute__((ext_vector_type(8))) __bf16 bf16x8;
typedef __attribute__((ext_vector_type(4))) float f32x4;
typedef __attribute__((ext_vector_type(16))) float f32x16;
typedef __attribute__((ext_vector_type(8))) unsigned short us8;

__device__ __forceinline__ unsigned short f2bf(float f) {
  union { float f; unsigned u; } v;
  v.f = f;
  unsigned r = v.u + 0x7fffu + ((v.u >> 16) & 1u);
  return (unsigned short)(r >> 16);
}

__device__ __forceinline__ unsigned cvtpk(float lo, float hi) {
  unsigned r;
  asm("v_cvt_pk_bf16_f32 %0, %1, %2" : "=v"(r) : "v"(lo), "v"(hi));
  return r;
}

// ws layout (float offsets):
//   [0, 4194304)        S1part[ocp(16)][1024 b][8 d][32 j] f32  (16 MB)
//   [4194304, 5242880)  w1a: frag fi=((d*64+og)*8+ks), 64 lanes x 8 bf16
//                       lane: o=og*32+(lane&31), k=ks*16+(lane>>5)*8 (k=98 -> b1)
//   [5242880, 5767168)  xa:  frag fi=((d*32+bg)*8+ks), b=bg*32+(lane&31) (k=98 -> 1.0)
//   [5767168, 6029312)  wca: frag fi=((d*64+og)*2+t), j=lane&31, o=og*32+t*16+(lane>>5)*8
//   [6029312, +4096)    spsum  (slot = (rest*8+d)*4 + wave, rest in [0,128))
//   [6033408, +4096)    spsq
//   [6037504, +256)     wcsum[d*32+j]

__global__ __launch_bounds__(256) void kcvt(
    const float* __restrict__ x, const float* __restrict__ W1,
    const float* __restrict__ b1, const float* __restrict__ Wc,
    unsigned short* __restrict__ w1a, unsigned short* __restrict__ xa,
    unsigned short* __restrict__ wca, float* __restrict__ wcsum) {
  const int bid = blockIdx.x, tid = threadIdx.x;
  if (bid < 1024) {  // W1 fragments (+bias as k=98)
    int chunk = bid * 256 + tid;  // [0, 262144)
    int lane = chunk & 63, ks = (chunk >> 6) & 7;
    int og = (chunk >> 9) & 63, d = chunk >> 15;
    int o = og * 32 + (lane & 31);
    int k0 = ks * 16 + (lane >> 5) * 8;
    const float* src = W1 + (size_t)(d * 2048 + o) * 98;
    float bias = b1[d * 2048 + o];
    us8 v;
#pragma unroll
    for (int e = 0; e < 8; ++e) {
      int k = k0 + e;
      float f = (k < 98) ? src[k] : ((k == 98) ? bias : 0.0f);
      v[e] = f2bf(f);
    }
    *(us8*)(w1a + (size_t)chunk * 8) = v;
  } else if (bid < 1536) {  // x fragments (+ones col; rows >= B_ all-zero)
    int chunk = (bid - 1024) * 256 + tid;  // [0, 131072)
    int lane = chunk & 63, ks = (chunk >> 6) & 7;
    int bg = (chunk >> 9) & 31, d = chunk >> 14;
    int b = bg * 32 + (lane & 31);
    int k0 = ks * 16 + (lane >> 5) * 8;
    us8 v;
    if (b < B_) {
      const float* src = x + (size_t)b * (D_ * PRE_) + d * 98;
#pragma unroll
      for (int e = 0; e < 8; ++e) {
        int k = k0 + e;
        float f = (k < 98) ? src[k] : ((k == 98) ? 1.0f : 0.0f);
        v[e] = f2bf(f);
      }
    } else {
#pragma unroll
      for (int e = 0; e < 8; ++e) v[e] = 0;
    }
    *(us8*)(xa + (size_t)chunk * 8) = v;
  } else if (bid < 1792) {  // Wc fragments
    int chunk = (bid - 1536) * 256 + tid;  // [0, 65536)
    int lane = chunk & 63, t = (chunk >> 6) & 1;
    int og = (chunk >> 7) & 63, d = chunk >> 13;
    int j = lane & 31;
    int o = og * 32 + t * 16 + (lane >> 5) * 8;
    const float* src = Wc + (size_t)(d * J_ + j) * NXT_ + o;
    us8 v;
#pragma unroll
    for (int e = 0; e < 8; ++e) v[e] = f2bf(src[e]);
    *(us8*)(wca + (size_t)chunk * 8) = v;
  } else {  // wcsum rows
    __shared__ float red[256];
    int dj = bid - 1792;
    const float* p = Wc + (size_t)dj * NXT_;
    float s = 0.0f;
    for (int i = tid; i < NXT_; i += 256) s += p[i];
    red[tid] = s;
    __syncthreads();
    for (int st = 128; st; st >>= 1) {
      if (tid < st) red[tid] += red[tid + st];
      __syncthreads();
    }
    if (tid == 0) wcsum[dj] = red[0];
  }
}

// 1024 blocks (8d x 16bt x 8oc), 4 blocks/CU, 4 waves/SIMD. No LDS.
// Wave (bh, ohh) owns a complete GEMM2 slice: 32 b-rows x 32 j over its
// 128-o range -> independent S1part partial, no cross-wave reduction.
__global__ __launch_bounds__(256, 4) void k1_reg(
    const unsigned short* __restrict__ w1a, const unsigned short* __restrict__ xa,
    const unsigned short* __restrict__ wca, float* __restrict__ S1part,
    float* __restrict__ spsum, float* __restrict__ spsq) {
  const int id = blockIdx.x;
  const int d = id & 7;        // XCD-pinned
  const int rest = id >> 3;    // 0..127
  const int bt = rest & 15, oc = rest >> 4;
  const int tid = threadIdx.x;
  const int w = tid >> 6, lane = tid & 63;
  const int bh = w & 1, ohh = w >> 1;
  const int l31 = lane & 31, hi = lane >> 5;
  const bool lo_half = (hi == 0);

  // x fragments for this wave's b-group (loaded once, reused 4x)
  const int bg = bt * 2 + bh;
  const unsigned short* xb = xa + ((size_t)(d * 32 + bg) * 8) * 512 + lane * 8;
  bf16x8 xf[8];
#pragma unroll
  for (int ks = 0; ks < 8; ++ks) xf[ks] = *(const bf16x8*)(xb + ks * 512);

  const int og0 = oc * 8 + ohh * 4;
  const unsigned short* w1b =
      w1a + ((size_t)(d * 64 + og0) * 8) * 512 + lane * 8;
  const unsigned short* wcb =
      wca + ((size_t)(d * 64 + og0) * 2) * 512 + lane * 8;

  f32x16 acc2 = {};
  float lsum = 0.0f, lsq = 0.0f;

#pragma unroll
  for (int ou = 0; ou < 4; ++ou) {
    bf16x8 wc0 = *(const bf16x8*)(wcb + (size_t)(ou * 2 + 0) * 512);
    bf16x8 wc1 = *(const bf16x8*)(wcb + (size_t)(ou * 2 + 1) * 512);

    // GEMM1: 32x32 (o x b), K=128, W1 frags streamed in 4-frag halves
    f32x16 acc = {};
#pragma unroll
    for (int h = 0; h < 2; ++h) {
      bf16x8 a4[4];
#pragma unroll
      for (int k4 = 0; k4 < 4; ++k4)
        a4[k4] = *(const bf16x8*)(w1b + (size_t)(ou * 8 + h * 4 + k4) * 512);
#pragma unroll
      for (int k4 = 0; k4 < 4; ++k4)
        acc = __builtin_amdgcn_mfma_f32_32x32x16_bf16(a4[k4], xf[h * 4 + k4],
                                                      acc, 0, 0, 0);
    }

    // epilogue: relu + stats + in-register P frags -> GEMM2
    float v[16];
#pragma unroll
    for (int r = 0; r < 16; ++r) {
      v[r] = fmaxf(acc[r], 0.0f);
      lsum += v[r];
      lsq = fmaf(v[r], v[r], lsq);
    }
#pragma unroll
    for (int t = 0; t < 2; ++t) {
      unsigned A0 = cvtpk(v[8 * t + 0], v[8 * t + 1]);
      unsigned A1 = cvtpk(v[8 * t + 2], v[8 * t + 3]);
      unsigned B0 = cvtpk(v[8 * t + 4], v[8 * t + 5]);
      unsigned B1 = cvtpk(v[8 * t + 6], v[8 * t + 7]);
      unsigned sA0 = __shfl_xor(A0, 32);
      unsigned sA1 = __shfl_xor(A1, 32);
      unsigned sB0 = __shfl_xor(B0, 32);
      unsigned sB1 = __shfl_xor(B1, 32);
      union { unsigned u[4]; bf16x8 v; } f;
      f.u[0] = lo_half ? A0 : sB0;
      f.u[1] = lo_half ? A1 : sB1;
      f.u[2] = lo_half ? sA0 : B0;
      f.u[3] = lo_half ? sA1 : B1;
      acc2 = __builtin_amdgcn_mfma_f32_32x32x16_bf16(t == 0 ? wc0 : wc1, f.v,
                                                     acc2, 0, 0, 0);
    }
  }

  // store this wave's complete partial: ocp = oc*2 + ohh
  {
    const int ocp = oc * 2 + ohh;
    const int b = bt * 64 + bh * 32 + l31;
    float* s1b = S1part + (((size_t)ocp * 1024 + b) * 8 + d) * 32;
#pragma unroll
    for (int g = 0; g < 4; ++g) {
      f32x4 s = {acc2[4 * g + 0], acc2[4 * g + 1], acc2[4 * g + 2],
                 acc2[4 * g + 3]};
      *(f32x4*)(s1b + 8 * g + 4 * hi) = s;
    }
  }

  // stats: per-wave shuffle reduction
#pragma unroll
  for (int off = 32; off; off >>= 1) {
    lsum += __shfl_down(lsum, off);
    lsq += __shfl_down(lsq, off);
  }
  if (lane == 0) {
    int slot = id * 4 + w;  // = (rest*8+d)*4 + w
    spsum[slot] = lsum;
    spsq[slot] = lsq;
  }
}

#define W3S 33
#define W4S 99

__global__ __launch_bounds__(256) void k3_tail(
    const float* __restrict__ S1part, const float* __restrict__ spsum,
    const float* __restrict__ spsq, const float* __restrict__ wcsum,
    const float* __restrict__ bc, const float* __restrict__ b_mat,
    const float* __restrict__ h_mat, const float* __restrict__ a_mat,
    const float* __restrict__ noise, const float* __restrict__ indicator,
    const float* __restrict__ cutb, const float* __restrict__ W3,
    const float* __restrict__ b3, const float* __restrict__ W4,
    const float* __restrict__ b4, const float* __restrict__ Wo,
    const float* __restrict__ bo, float* __restrict__ out) {
  __shared__ float W3l[98 * W3S];
  __shared__ float W4l[49 * W4S];
  __shared__ float Wol[10 * 49];
  __shared__ float b3l[98], b4l[49], bol[10];
  __shared__ float cutl[32], coefl[256], konstl[32];
  __shared__ float psum[8][33], psq[8][33];
  __shared__ float mvals[8], vvals[8];
  __shared__ float sh_gm, sh_inv;
  __shared__ float offs[D_][J_];
  __shared__ float h1[8][32];
  __shared__ float h2[8][100];
  __shared__ float h3[8][52];
  __shared__ float lg[8][10];
  __shared__ float lsel[8];

  const int tid = threadIdx.x;

  for (int idx = tid; idx < 98 * 32; idx += 256) {
    int o = idx >> 5, j = idx & 31;
    W3l[o * W3S + j] = W3[idx];
  }
  for (int idx = tid; idx < 49 * 98; idx += 256) {
    int o = idx / 98, k = idx - o * 98;
    W4l[o * W4S + k] = W4[idx];
  }
  for (int idx = tid; idx < 490; idx += 256) Wol[idx] = Wo[idx];
  if (tid < 98) b3l[tid] = b3[tid];
  if (tid < 49) b4l[tid] = b4[tid];
  if (tid < 10) bol[tid] = bo[tid];
  if (tid < 32) cutl[tid] = cutb[tid];

  // stats reduce: 256 threads x 16 loads (dd = tid>>5, i = tid&31)
  {
    int dd = tid >> 5, i = tid & 31;
    float s = 0.0f, q = 0.0f;
#pragma unroll
    for (int m = 0; m < 4; ++m) {
      int k = i + m * 32;  // rest index [0,128)
      int base = (k * 8 + dd) * 4;
#pragma unroll
      for (int ww = 0; ww < 4; ++ww) {
        s += spsum[base + ww];
        q += spsq[base + ww];
      }
    }
    psum[dd][i] = s;
    psq[dd][i] = q;
  }
  __syncthreads();
  if (tid < 8) {
    float s = 0.0f, q = 0.0f;
#pragma unroll
    for (int i = 0; i < 32; ++i) {
      s += psum[tid][i];
      q += psq[tid][i];
    }
    const float inv_cnt = 1.0f / ((float)B_ * (float)NXT_);
    float m = s * inv_cnt;
    mvals[tid] = m;
    vvals[tid] = q * inv_cnt - m * m;
  }
  __syncthreads();
  if (tid == 0) {
    float gm = 0.0f, gv = 0.0f;
    for (int dd = 0; dd < 8; ++dd) {
      gm += mvals[dd];
      gv += vvals[dd];
    }
    gm *= 0.125f;
    gv *= 0.125f;
    sh_gm = gm;
    sh_inv = 1.0f / sqrtf(gv + 1e-6f);
  }
  __syncthreads();
  {
    int dd = tid >> 5, j = tid & 31;
    float hs[A_] = {0, 0, 0, 0, 0};
    for (int k = 0; k < K_; ++k) {
      float indv = indicator[j * K_ + k];
      if (indv != 0.0f) {
        const float* hp = h_mat + ((size_t)dd * K_ + k) * A_;
#pragma unroll
        for (int a = 0; a < A_; ++a) hs[a] = fmaf(indv, hp[a], hs[a]);
      }
    }
    float hv = 0.0f;
#pragma unroll
    for (int a = 0; a < A_; ++a) hv = fmaf(hs[a], a_mat[j * A_ + a], hv);
    float c = b_mat[dd * J_ + j] * hv;
    coefl[tid] = c * sh_inv;
    offs[dd][j] = c * (bc[dd * J_ + j] - sh_gm * wcsum[dd * J_ + j] * sh_inv);
  }
  __syncthreads();
  if (tid < J_) {
    float nz = 0.0f;
#pragma unroll
    for (int a = 0; a < A_; ++a)
      nz = fmaf(a_mat[tid * A_ + a], noise[tid * A_ + a], nz);
    float s = nz;
#pragma unroll
    for (int dd = 0; dd < D_; ++dd) s += offs[dd][tid];
    konstl[tid] = s;
  }
  __syncthreads();

  const int row = tid >> 5, lane = tid & 31;
  const int b = blockIdx.x * 8 + row;  // 125*8 = 1000 exactly

  float rsum = konstl[lane];
#pragma unroll
  for (int dd = 0; dd < D_; ++dd) {
    float s = 0.0f;
#pragma unroll
    for (int p = 0; p < 16; ++p)
      s += S1part[(((size_t)p * 1024 + b) * 8 + dd) * 32 + lane];
    rsum = fmaf(coefl[dd * J_ + lane], s, rsum);
  }
  h1[row][lane] = fmaxf(rsum + cutl[lane], 0.0f);
  __syncthreads();

  for (int o = lane; o < 98; o += 32) {
    float a = b3l[o];
#pragma unroll
    for (int j = 0; j < 32; ++j) a = fmaf(h1[row][j], W3l[o * W3S + j], a);
    h2[row][o] = fmaxf(a, 0.0f);
  }
  __syncthreads();

  for (int o = lane; o < 49; o += 32) {
    float a = b4l[o];
    for (int k = 0; k < 98; ++k) a = fmaf(h2[row][k], W4l[o * W4S + k], a);
    h3[row][o] = fmaxf(a, 0.0f);
  }
  __syncthreads();

  if (lane < 10) {
    float a = bol[lane];
#pragma unroll
    for (int k = 0; k < 49; ++k) a = fmaf(h3[row][k], Wol[lane * 49 + k], a);
    lg[row][lane] = a;
  }
  __syncthreads();
  if (lane == 0) {
    float mx = lg[row][0];
    for (int i = 1; i < 10; ++i) mx = fmaxf(mx, lg[row][i]);
    float se = 0.0f;
    for (int i = 0; i < 10; ++i) se += expf(lg[row][i] - mx);
    lsel[row] = mx + logf(se);
  }
  __syncthreads();
  if (lane < 10) out[(size_t)b * 10 + lane] = lg[row][lane] - lsel[row];
}

extern "C" void kernel_launch(void* const* d_in, const int* in_sizes, int n_in,
                              void* d_out, int out_size, void* d_ws,
                              size_t ws_size, hipStream_t stream) {
  const float* x = (const float*)d_in[0];
  const float* W1 = (const float*)d_in[1];
  const float* b1 = (const float*)d_in[2];
  const float* Wc = (const float*)d_in[3];
  const float* bc = (const float*)d_in[4];
  const float* cutb = (const float*)d_in[5];
  const float* bmat = (const float*)d_in[6];
  const float* hmat = (const float*)d_in[7];
  const float* amat = (const float*)d_in[8];
  const float* noise = (const float*)d_in[9];
  const float* W3 = (const float*)d_in[10];
  const float* b3 = (const float*)d_in[11];
  const float* W4 = (const float*)d_in[12];
  const float* b4 = (const float*)d_in[13];
  const float* Wo = (const float*)d_in[14];
  const float* bo = (const float*)d_in[15];
  const float* ind = (const float*)d_in[16];

  float* ws = (float*)d_ws;
  float* S1part = ws;                                      // [0, 4194304)
  unsigned short* w1a = (unsigned short*)(ws + 4194304);   // 2,097,152 us
  unsigned short* xa = (unsigned short*)(ws + 5242880);    // 1,048,576 us
  unsigned short* wca = (unsigned short*)(ws + 5767168);   // 524,288 us
  float* spsum = ws + 6029312;                             // 4096
  float* spsq = ws + 6033408;                              // 4096
  float* wcsum = ws + 6037504;                             // 256

  kcvt<<<2048, 256, 0, stream>>>(x, W1, b1, Wc, w1a, xa, wca, wcsum);
  k1_reg<<<1024, 256, 0, stream>>>(w1a, xa, wca, S1part, spsum, spsq);
  k3_tail<<<125, 256, 0, stream>>>(S1part, spsum, spsq, wcsum, bc, bmat, hmat,
                                   amat, noise, ind, cutb, W3, b3, W4, b4, Wo,
                                   bo, (float*)d_out);
}